// Round 13
// baseline (610.907 us; speedup 1.0000x reference)
//
#include <hip/hip_runtime.h>
#include <hip/hip_bf16.h>

#define DEMB 64
typedef unsigned short u16;
typedef float f32x2 __attribute__((ext_vector_type(2)));

__device__ __forceinline__ unsigned f2bf(float f) {
    union { float f; unsigned int i; } c; c.f = f;
    unsigned int r = c.i + 0x7FFF + ((c.i >> 16) & 1);
    return r >> 16;
}
__device__ __forceinline__ float lo16(unsigned int w) {
    union { unsigned int i; float f; } c; c.i = w << 16; return c.f;
}
__device__ __forceinline__ float hi16(unsigned int w) {
    union { unsigned int i; float f; } c; c.i = w & 0xFFFF0000u; return c.f;
}

// odd 7th-order minimax tanh on [-1.02, 1.02], abs err <= ~3e-4
__device__ __forceinline__ float ptanh5(float a) {
    float a2 = a * a;
    float t = fmaf(a2, -0.030095f, 0.124066f);
    t = fmaf(a2, t, -0.332377f);
    t = fmaf(a2, t, 1.0f);
    return a * t;
}

__global__ void init_A_kernel(float4* __restrict__ A, int E) {
    int e = blockIdx.x * blockDim.x + threadIdx.x;
    if (e < E) A[e] = make_float4(1.f, 1.f, 1.f, 1.f);
}

__global__ void concat_copy_kernel(const float* __restrict__ u, const float* __restrict__ it,
                                   float* __restrict__ x, float* __restrict__ acc,
                                   int nu_elems, int total) {
    int i = blockIdx.x * blockDim.x + threadIdx.x;
    if (i >= total) return;
    float v = (i < nu_elems) ? u[i] : it[i - nu_elems];
    x[i] = v;
    acc[i] = v;
}

// ============ CSR build: deterministic histogram radix (R9-proven) ============
__global__ void hist_kernel(const int* __restrict__ h, int* __restrict__ ghist,
                            int E, int EPB, int NB) {
    __shared__ int bins[1024];
    int b = blockIdx.x, tid = threadIdx.x;
    for (int j = tid; j < NB; j += 256) bins[j] = 0;
    __syncthreads();
    int s = b * EPB, e = min(s + EPB, E);
    for (int k = s + tid; k < e; k += 256)
        atomicAdd(&bins[((unsigned)h[k]) >> 8], 1);
    __syncthreads();
    for (int j = tid; j < NB; j += 256) ghist[j * gridDim.x + b] = bins[j];
}

__global__ void btot_kernel(const int* __restrict__ ghist, int* __restrict__ btot) {
    __shared__ int s[256];
    int j = blockIdx.x, tid = threadIdx.x;
    s[tid] = ghist[j * 256 + tid];
    __syncthreads();
    for (int o = 128; o >= 1; o >>= 1) {
        if (tid < o) s[tid] += s[tid + o];
        __syncthreads();
    }
    if (tid == 0) btot[j] = s[0];
}

__global__ void bscan_kernel(const int* __restrict__ btot, int* __restrict__ bbase,
                             int NB, int E) {
    __shared__ int s[1024];
    int tid = threadIdx.x;
    int v = (tid < NB) ? btot[tid] : 0;
    s[tid] = v;
    __syncthreads();
    for (int o = 1; o < 1024; o <<= 1) {
        int a = (tid >= o) ? s[tid - o] : 0;
        __syncthreads();
        s[tid] += a;
        __syncthreads();
    }
    if (tid < NB) bbase[tid] = s[tid] - v;
    if (tid == 0) bbase[NB] = E;
}

__global__ void bofs_kernel(int* __restrict__ ghist, const int* __restrict__ bbase) {
    __shared__ int s[256];
    int j = blockIdx.x, tid = threadIdx.x;
    int v = ghist[j * 256 + tid];
    s[tid] = v;
    __syncthreads();
    for (int o = 1; o < 256; o <<= 1) {
        int a = (tid >= o) ? s[tid - o] : 0;
        __syncthreads();
        s[tid] += a;
        __syncthreads();
    }
    ghist[j * 256 + tid] = bbase[j] + s[tid] - v;
}

__global__ void scatter_kernel(const int* __restrict__ h, const int* __restrict__ t,
                               const int* __restrict__ ghist, unsigned* __restrict__ stg,
                               int E, int EPB, int NB) {
    __shared__ int cur[1024];
    int b = blockIdx.x, tid = threadIdx.x;
    for (int j = tid; j < NB; j += 256) cur[j] = ghist[j * gridDim.x + b];
    __syncthreads();
    int s = b * EPB, e = min(s + EPB, E);
    for (int k = s + tid; k < e; k += 256) {
        unsigned hh = (unsigned)h[k];
        int pos = atomicAdd(&cur[hh >> 8], 1);
        stg[pos] = ((hh & 255u) << 18) | (unsigned)t[k];
    }
}

__global__ void finalize_kernel(const unsigned* __restrict__ stg, const int* __restrict__ bbase,
                                int* __restrict__ off, int* __restrict__ csr_t, int N, int E) {
    __shared__ int cnt[256];
    __shared__ int scn[256];
    int b = blockIdx.x, tid = threadIdx.x;
    int ebeg = bbase[b], eend = bbase[b + 1];
    cnt[tid] = 0;
    __syncthreads();
    for (int k = ebeg + tid; k < eend; k += 256)
        atomicAdd(&cnt[(stg[k] >> 18) & 255u], 1);
    __syncthreads();
    int v = cnt[tid];
    scn[tid] = v;
    __syncthreads();
    for (int o = 1; o < 256; o <<= 1) {
        int a = (tid >= o) ? scn[tid - o] : 0;
        __syncthreads();
        scn[tid] += a;
        __syncthreads();
    }
    int excl = scn[tid] - v;
    int gn = (b << 8) + tid;
    if (gn < N) off[gn] = ebeg + excl;
    if (b == 0 && tid == 0) off[N] = E;
    __syncthreads();
    cnt[tid] = excl;   // reuse as cursor
    __syncthreads();
    for (int k = ebeg + tid; k < eend; k += 256) {
        unsigned en = stg[k];
        int slot = atomicAdd(&cnt[(en >> 18) & 255u], 1);
        csr_t[ebeg + slot] = (int)(en & 0x3FFFFu);
    }
}

// bootstrap: prob=0.25 folded -> dcol0 = 0.5/sqrt(deg)
__global__ void dcol0_kernel(const int* __restrict__ off, float* __restrict__ dcol, int N) {
    int n = blockIdx.x * blockDim.x + threadIdx.x;
    if (n >= N) return;
    float v = 0.5f * rsqrtf((float)(off[n + 1] - off[n]));
    *(float4*)(dcol + (size_t)n * 4) = make_float4(v, v, v, v);
}

// ============ per-layer: xt[i] = (bf16(tanh(x/||x_f||)) << 16) | bf16(x)
__global__ void prep_kernel(const float* __restrict__ x, unsigned* __restrict__ xt, int total) {
    int i = blockIdx.x * blockDim.x + threadIdx.x;
    if (i >= total) return;
    float v = x[i];
    float s = v * v;
#pragma unroll
    for (int o = 8; o >= 1; o >>= 1) s += __shfl_xor(s, o);
    float nr = fmaxf(sqrtf(s), 1e-12f);
    unsigned tb = f2bf(ptanh5(v * __builtin_amdgcn_rcpf(nr)));
    xt[i] = (tb << 16) | f2bf(v);
}

// ============ fused message + routing + next-iteration softmax/dcol
// One 64-lane wave per node. lane l: g=l>>4 (edge slot), m=l&15 (col quad), f=m>>2.
// xt packs xs (lo16) + tail (hi16): ONE uint4 gather per lane per edge serves
// both loops. First 16 edges cached in named uint4 regs -> loop2 re-gathers
// only deg>16 overflow (~15% of edges).
// ACC: 0=none, 1=acc+=val, 2=acc=(acc+val)/3 (final mean)
template <bool UNI, bool WOUT, bool ROUTE, int ACC>
__global__ void message_kernel(const int* __restrict__ off, const int* __restrict__ csr_t,
                               float* __restrict__ Acsr, float* __restrict__ prob,
                               const unsigned* __restrict__ xt,
                               const float* __restrict__ dcol_in, float* __restrict__ dcol_out,
                               float* __restrict__ out, float* __restrict__ acc, int N) {
    int gid = blockIdx.x * blockDim.x + threadIdx.x;
    int n = gid >> 6;
    if (n >= N) return;
    int l = gid & 63;
    int g = l >> 4;
    int m = l & 15;
    unsigned f = (unsigned)(m >> 2);
    int s = off[n], e = off[n + 1];
    unsigned moff = (unsigned)(m << 2);   // u32 index within the 64-wide row

    f32x2 a01 = {0.f, 0.f}, a23 = {0.f, 0.f};

    auto trip = [&](int kbase, uint4& w) {
        int e1 = kbase + g;
        bool v1 = e1 < e;
        unsigned c1 = (unsigned)(v1 ? e1 : s);
        unsigned t1 = (unsigned)csr_t[c1];
        float p1;
        if (UNI) p1 = dcol_in[t1 * 4u + f];
        else     p1 = prob[c1 * 4u + f] * dcol_in[t1 * 4u + f];
        p1 = v1 ? p1 : 0.f;
        w = *(const uint4*)(xt + (t1 << 6) + moff);
        a01 += p1 * (f32x2){lo16(w.x), lo16(w.y)};   // v_pk_fma_f32
        a23 += p1 * (f32x2){lo16(w.z), lo16(w.w)};
    };

    // cached trips (16 edges, static register indexing)
    uint4 w0, w1, w2, w3;
    trip(s, w0);
    trip(s + 4, w1);
    trip(s + 8, w2);
    trip(s + 12, w3);
#pragma unroll 2
    for (int k = s + 16; k < e; k += 4) {
        uint4 wt;
        trip(k, wt);
    }

    float a0 = a01.x, a1 = a01.y, a2 = a23.x, a3 = a23.y;
    // combine the 4 edge slots
    a0 += __shfl_xor(a0, 16); a1 += __shfl_xor(a1, 16);
    a2 += __shfl_xor(a2, 16); a3 += __shfl_xor(a3, 16);
    a0 += __shfl_xor(a0, 32); a1 += __shfl_xor(a1, 32);
    a2 += __shfl_xor(a2, 32); a3 += __shfl_xor(a3, 32);

    if (WOUT || ACC != 0) {
        float dn = dcol_in[(unsigned)n * 4u + f];
        if (l < 16) {
            unsigned oidx = ((unsigned)n << 6) + moff;
            float4 val = make_float4(a0 * dn, a1 * dn, a2 * dn, a3 * dn);
            if (WOUT) *(float4*)(out + oidx) = val;
            if (ACC == 1) {
                float4 c = *(const float4*)(acc + oidx);
                *(float4*)(acc + oidx) =
                    make_float4(c.x + val.x, c.y + val.y, c.z + val.z, c.w + val.w);
            } else if (ACC == 2) {
                const float k3 = 1.0f / 3.0f;
                float4 c = *(const float4*)(acc + oidx);
                *(float4*)(acc + oidx) =
                    make_float4((c.x + val.x) * k3, (c.y + val.y) * k3,
                                (c.z + val.z) * k3, (c.w + val.w) * k3);
            }
        }
    }
    if (!ROUTE) return;

    // head = l2norm per factor (dcol[n] scale-invariant)
    float ss = a0 * a0 + a1 * a1 + a2 * a2 + a3 * a3;
    ss += __shfl_xor(ss, 1);
    ss += __shfl_xor(ss, 2);
    float inv = 1.0f / fmaxf(sqrtf(ss), 1e-12f);
    f32x2 h01 = {a0 * inv, a1 * inv};
    f32x2 h23 = {a2 * inv, a3 * inv};

    float rowsumf = 0.f;

    auto route = [&](int kbase, const uint4& w) {
        int e1 = kbase + g;
        bool v1 = e1 < e;
        unsigned c1 = (unsigned)(v1 ? e1 : s);
        f32x2 dv = h01 * (f32x2){hi16(w.x), hi16(w.y)}
                 + h23 * (f32x2){hi16(w.z), hi16(w.w)};
        float d1 = dv.x + dv.y;
        d1 += __shfl_xor(d1, 1); d1 += __shfl_xor(d1, 2);
        unsigned ai = c1 * 4u + f;
        float na = Acsr[ai] + d1;
        float ex = __expf(na);               // no max-sub: |A|<=13 analytically
        float se = ex + __shfl_xor(ex, 4); se += __shfl_xor(se, 8);
        float p = ex * __builtin_amdgcn_rcpf(se);
        if ((m & 3) == 0 && v1) { Acsr[ai] = na; prob[ai] = p; }
        rowsumf += v1 ? p : 0.f;
    };

    route(s, w0);          // cached: zero re-gather
    route(s + 4, w1);
    route(s + 8, w2);
    route(s + 12, w3);
#pragma unroll 2
    for (int k = s + 16; k < e; k += 4) {
        int e1 = k + g;
        unsigned c1 = (unsigned)((e1 < e) ? e1 : s);
        unsigned t1 = (unsigned)csr_t[c1];
        uint4 wt = *(const uint4*)(xt + (t1 << 6) + moff);
        route(k, wt);
    }

    rowsumf += __shfl_xor(rowsumf, 16);
    rowsumf += __shfl_xor(rowsumf, 32);
    if (l < 16 && (m & 3) == 0) dcol_out[(unsigned)n * 4u + f] = rsqrtf(rowsumf);
}

extern "C" void kernel_launch(void* const* d_in, const int* in_sizes, int n_in,
                              void* d_out, int out_size, void* d_ws, size_t ws_size,
                              hipStream_t stream) {
    const float* user_emb = (const float*)d_in[0];
    const float* item_emb = (const float*)d_in[1];
    const int* h = (const int*)d_in[2];
    const int* t = (const int*)d_in[3];

    const int nu_elems = in_sizes[0];
    const int ni_elems = in_sizes[1];
    const int total = nu_elems + ni_elems;   // N * 64
    const int N = total / DEMB;
    const int E = in_sizes[2];
    const int NB = (N + 255) >> 8;           // buckets (<= 1024)
    const int NBLK = 256;
    const int EPB = (E + NBLK - 1) / NBLK;

    float* acc = (float*)d_out;

    // ---- workspace layout ----
    float* x     = (float*)d_ws;                    // total f32
    float* out   = x + (size_t)total;               // total f32
    float* Acsr  = out + (size_t)total;             // 4E f32
    float* prob  = Acsr + (size_t)4 * E;            // 4E f32 (first E aliased as stg)
    float* dcolA = prob + (size_t)4 * E;            // 4N f32
    float* dcolB = dcolA + (size_t)4 * N;           // 4N f32
    unsigned* xt = (unsigned*)(dcolB + (size_t)4 * N); // total u32 (packed xs|tail)
    int* ghist   = (int*)(xt + (size_t)total);      // NB*256
    int* btot    = ghist + (size_t)NB * 256;        // NB
    int* bbase   = btot + ((NB + 3) & ~3);          // NB+1
    int* off     = bbase + ((NB + 5) & ~3);         // N+1
    int* csr_t   = off + ((N + 4) & ~3);            // E
    unsigned* stg = (unsigned*)prob;                // E (time-disjoint with prob)

    const int BLK = 256;
    const int gE = (E + BLK - 1) / BLK;
    const int gTot = (total + BLK - 1) / BLK;
    const int gN = (N + BLK - 1) / BLK;
    const int gNodeWave = (N * 64 + BLK - 1) / BLK;

    concat_copy_kernel<<<gTot, BLK, 0, stream>>>(user_emb, item_emb, x, acc, nu_elems, total);

    // CSR build (deterministic, no contended global atomics)
    hist_kernel<<<NBLK, 256, 0, stream>>>(h, ghist, E, EPB, NB);
    btot_kernel<<<NB, 256, 0, stream>>>(ghist, btot);
    bscan_kernel<<<1, 1024, 0, stream>>>(btot, bbase, NB, E);
    bofs_kernel<<<NB, 256, 0, stream>>>(ghist, bbase);
    scatter_kernel<<<NBLK, 256, 0, stream>>>(h, t, ghist, stg, E, EPB, NB);
    finalize_kernel<<<NB, 256, 0, stream>>>(stg, bbase, off, csr_t, N, E);

    init_A_kernel<<<gE, BLK, 0, stream>>>((float4*)Acsr, E);
    dcol0_kernel<<<gN, BLK, 0, stream>>>(off, dcolA, N);

    // ---- layer 0 ----
    prep_kernel<<<gTot, BLK, 0, stream>>>(x, xt, total);
    message_kernel<true, false, true, 0><<<gNodeWave, BLK, 0, stream>>>(
        off, csr_t, Acsr, prob, xt, dcolA, dcolB, out, acc, N);
    message_kernel<false, true, true, 1><<<gNodeWave, BLK, 0, stream>>>(
        off, csr_t, Acsr, prob, xt, dcolB, dcolA, out, acc, N);

    // ---- layer 1 ----
    prep_kernel<<<gTot, BLK, 0, stream>>>(out, xt, total);
    message_kernel<false, false, true, 0><<<gNodeWave, BLK, 0, stream>>>(
        off, csr_t, Acsr, prob, xt, dcolA, dcolB, x, acc, N);
    message_kernel<false, false, false, 2><<<gNodeWave, BLK, 0, stream>>>(
        off, csr_t, Acsr, prob, xt, dcolB, dcolA, x, acc, N);
}